// Round 4
// baseline (264.145 us; speedup 1.0000x reference)
//
#include <hip/hip_runtime.h>
#include <stdint.h>

// B=2, S=2048, D=768, H=12, hd=64
typedef float v4f __attribute__((ext_vector_type(4)));
typedef short v8s __attribute__((ext_vector_type(8)));

#define AS1 __attribute__((address_space(1)))
#define AS3 __attribute__((address_space(3)))

__device__ __forceinline__ void load16_to_lds(const void* g, void* l) {
  __builtin_amdgcn_global_load_lds((AS1 void*)g, (AS3 void*)l, 16, 0, 0);
}
__device__ __forceinline__ void load4_to_lds(const void* g, void* l) {
  __builtin_amdgcn_global_load_lds((AS1 void*)g, (AS3 void*)l, 4, 0, 0);
}

__device__ __forceinline__ float fexp2(float x) {
#if __has_builtin(__builtin_amdgcn_exp2f)
  return __builtin_amdgcn_exp2f(x);
#else
  return exp2f(x);
#endif
}

// round-half-up fp32 -> bf16
__device__ __forceinline__ unsigned short f2bf_rn(float f) {
  union { float f; uint32_t u; } v; v.f = f;
  return (unsigned short)((v.u + 0x8000u) >> 16);
}
// pack two fp32 -> bf16x2 dword via v_perm (x in low half)
__device__ __forceinline__ uint32_t pack_bf2(float x, float y) {
  union { float f; uint32_t u; } a, b; a.f = x; b.f = y;
  return __builtin_amdgcn_perm(b.u + 0x8000u, a.u + 0x8000u, 0x07060302u);
}

#define QSCALE 0.052058786f  // log2(e)/sqrt(768), folded into Wq & bq

// ---------------------------------------------------------------------------
// Kernel 1: fused convert (y=0..6) + mask pack (y=7).
// Weights fp32->bf16 (Wq pre-scaled), inputs fp32->bf16, mask -> 1 bit.
// ---------------------------------------------------------------------------
__global__ __launch_bounds__(256) void conv_pack_kernel(
    const float* __restrict__ wk, const float* __restrict__ wq,
    const float* __restrict__ wv, const float* __restrict__ wc,
    const float* __restrict__ kin, const float* __restrict__ qin,
    const float* __restrict__ vin, const uint32_t* __restrict__ mask,
    unsigned short* __restrict__ dk, unsigned short* __restrict__ dq,
    unsigned short* __restrict__ dv, unsigned short* __restrict__ dc,
    unsigned short* __restrict__ dki, unsigned short* __restrict__ dqi,
    unsigned short* __restrict__ dvi, uint32_t* __restrict__ bits) {
  const int y = blockIdx.y;
  const int tid = threadIdx.x;
  if (y == 7) {  // mask pack
    if (blockIdx.x >= 1024) return;
    __shared__ int s_i32;
    if (tid == 0) s_i32 = 1;
    __syncthreads();
    if (mask[tid] > 1u) s_i32 = 0;  // byte-mode detector (P(fail)=8^-256)
    __syncthreads();
    if (s_i32) {
      const int lane = tid & 63;
      const int gw = (blockIdx.x * 256 + tid) >> 6;  // 0..4095
#pragma unroll 4
      for (int it = 0; it < 32; ++it) {
        const size_t base = (size_t)gw * 2048 + it * 64;
        unsigned long long bal = __ballot(mask[base + lane] != 0u);
        if (lane == 0) *(unsigned long long*)&bits[base >> 5] = bal;
      }
    } else {
      const int wi = blockIdx.x * 256 + tid;
      const uint32_t* p = mask + (size_t)wi * 8;
      uint32_t w = 0;
#pragma unroll
      for (int j8 = 0; j8 < 8; ++j8) {
        uint32_t u = p[j8];
#pragma unroll
        for (int k = 0; k < 4; ++k)
          w |= (((u >> (8 * k)) & 0xFFu) ? 1u : 0u) << (j8 * 4 + k);
      }
      bits[wi] = w;
    }
    return;
  }
  const float* s; unsigned short* d; float sc = 1.f; int n4;
  switch (y) {
    case 0: s = wk;  d = dk;  n4 = 147456; break;
    case 1: s = wq;  d = dq;  n4 = 147456; sc = QSCALE; break;
    case 2: s = wv;  d = dv;  n4 = 147456; break;
    case 3: s = wc;  d = dc;  n4 = 147456; break;
    case 4: s = kin; d = dki; n4 = 786432; break;
    case 5: s = qin; d = dqi; n4 = 786432; break;
    default: s = vin; d = dvi; n4 = 786432; break;
  }
  const int i = blockIdx.x * 256 + tid;
  if (i >= n4) return;
  float4 f = ((const float4*)s)[i];
  uint2 o;
  o.x = pack_bf2(f.x * sc, f.y * sc);
  o.y = pack_bf2(f.z * sc, f.w * sc);
  ((uint2*)d)[i] = o;
}

// ---------------------------------------------------------------------------
// Kernel 2: QKV GEMM, all-bf16, global_load_lds staging, dbuf single-barrier.
// 128x128 tile, BK=32, 4 waves 4x4 MFMA.
// z=0: Qin*Wq(scaled) -> Qb ; z=1: Kin*Wk -> Kb ; z=2: Vin*Wv -> Vt (transposed)
// ---------------------------------------------------------------------------
__global__ __launch_bounds__(256, 3) void gemm_qkv_kernel(
    const unsigned short* __restrict__ qin, const unsigned short* __restrict__ kin,
    const unsigned short* __restrict__ vin,
    const unsigned short* __restrict__ wqb, const unsigned short* __restrict__ wkb,
    const unsigned short* __restrict__ wvb,
    const float* __restrict__ bq, const float* __restrict__ bk,
    const float* __restrict__ bv,
    unsigned short* __restrict__ Qb, unsigned short* __restrict__ Kb,
    unsigned short* __restrict__ Vt) {
  const int which = blockIdx.z;
  const unsigned short* A; const unsigned short* Wb; const float* bias;
  float bscale = 1.f;
  if (which == 0)      { A = qin; Wb = wqb; bias = bq; bscale = QSCALE; }
  else if (which == 1) { A = kin; Wb = wkb; bias = bk; }
  else                 { A = vin; Wb = wvb; bias = bv; }

  const int m0 = blockIdx.x * 128, n0 = blockIdx.y * 128;
  const int tid = threadIdx.x, lane = tid & 63, wid = tid >> 6;
  const int wm = wid >> 1, wn = wid & 1;
  const int l16 = lane & 15, quad = lane >> 4;

  __shared__ __align__(16) unsigned short As[2][128 * 32];
  __shared__ __align__(16) unsigned short Bs[2][128 * 32];

  v4f acc[4][4];
#pragma unroll
  for (int i = 0; i < 4; ++i)
#pragma unroll
    for (int j = 0; j < 4; ++j) { v4f z = {0.f, 0.f, 0.f, 0.f}; acc[i][j] = z; }

  const int c0 = wid * 128 + lane, c1 = wid * 128 + 64 + lane;
  const unsigned short* a0 = A + (size_t)(m0 + (c0 >> 2)) * 768 + (c0 & 3) * 8;
  const unsigned short* a1 = A + (size_t)(m0 + (c1 >> 2)) * 768 + (c1 & 3) * 8;
  const unsigned short* b0 = Wb + (size_t)(n0 + (c0 >> 2)) * 768 + (c0 & 3) * 8;
  const unsigned short* b1 = Wb + (size_t)(n0 + (c1 >> 2)) * 768 + (c1 & 3) * 8;

#define QKV_STAGE(k0, buf)                                         \
  do {                                                             \
    load16_to_lds(a0 + (k0), &As[buf][(wid * 128) * 8]);           \
    load16_to_lds(a1 + (k0), &As[buf][(wid * 128 + 64) * 8]);      \
    load16_to_lds(b0 + (k0), &Bs[buf][(wid * 128) * 8]);           \
    load16_to_lds(b1 + (k0), &Bs[buf][(wid * 128 + 64) * 8]);      \
  } while (0)

  QKV_STAGE(0, 0);
#pragma unroll 2
  for (int ks = 0; ks < 24; ++ks) {
    const int bufc = ks & 1;
    __syncthreads();
    v8s af[4], bf[4];
#pragma unroll
    for (int i = 0; i < 4; ++i)
      af[i] = *(const v8s*)&As[bufc][(wm * 64 + i * 16 + l16) * 32 + quad * 8];
#pragma unroll
    for (int j = 0; j < 4; ++j)
      bf[j] = *(const v8s*)&Bs[bufc][(wn * 64 + j * 16 + l16) * 32 + quad * 8];
    if (ks < 23) QKV_STAGE((ks + 1) * 32, bufc ^ 1);
#pragma unroll
    for (int i = 0; i < 4; ++i)
#pragma unroll
      for (int j = 0; j < 4; ++j)
        acc[i][j] = __builtin_amdgcn_mfma_f32_16x16x32_bf16(af[i], bf[j],
                                                            acc[i][j], 0, 0, 0);
  }
#undef QKV_STAGE

#pragma unroll
  for (int i = 0; i < 4; ++i) {
#pragma unroll
    for (int j = 0; j < 4; ++j) {
      const int mbase = m0 + wm * 64 + i * 16 + quad * 4;
      const int n = n0 + wn * 64 + j * 16 + l16;
      const float bv_ = bias[n] * bscale;
      if (which == 2) {
        const int bb = mbase >> 11, ss = mbase & 2047;
        uint2 pk;
        pk.x = pack_bf2(acc[i][j][0] + bv_, acc[i][j][1] + bv_);
        pk.y = pack_bf2(acc[i][j][2] + bv_, acc[i][j][3] + bv_);
        *(uint2*)&Vt[((size_t)bb * 768 + n) * 2048 + ss] = pk;
      } else {
        unsigned short* dst = (which == 0) ? Qb : Kb;
#pragma unroll
        for (int r = 0; r < 4; ++r)
          dst[(size_t)(mbase + r) * 768 + n] = f2bf_rn(acc[i][j][r] + bv_);
      }
    }
  }
}

// ---------------------------------------------------------------------------
// Kernel 3: attention, 2x2 wave split. Wave (wq,wk): q-rows 32wq..+31, keys
// 32wk..+31 of each 64-key tile. Disjoint-key partials (o, ol) are linear ->
// combined once in an LDS epilogue reduction. Halves K/V fragment LDS traffic.
// No-max exp2 softmax (scale folded into Wq), denominator via ones-MFMA,
// XOR-swizzled LDS, dbuf single-barrier prefetch. grid (32,12,2) x 256.
// ---------------------------------------------------------------------------
__global__ __launch_bounds__(256, 3) void attn_kernel(
    const unsigned short* __restrict__ Qb, const unsigned short* __restrict__ Kb,
    const unsigned short* __restrict__ Vt, const uint32_t* __restrict__ mbits,
    unsigned short* __restrict__ X) {
  const int q0 = blockIdx.x * 64;
  const int h = blockIdx.y, b = blockIdx.z;
  const int tid = threadIdx.x, w = tid >> 6, lane = tid & 63;
  const int l16 = lane & 15, quad = lane >> 4, l7 = l16 & 7;
  const int wq = w >> 1, wk = w & 1;

  // manual shared layout so the epilogue can alias Kl+Vl as fp32 scratch
  __shared__ __align__(16) char smem[41984];
  unsigned short* Kl = (unsigned short*)smem;             // [2][64*64] 16 KB
  unsigned short* Vl = (unsigned short*)(smem + 16384);   // [2][64*64] 16 KB
  unsigned short* Pl = (unsigned short*)(smem + 32768);   // [64*64]     8 KB
  uint32_t*       Ml = (uint32_t*)(smem + 40960);         // [2][128]    1 KB
  float*          sc = (float*)smem;                      // epilogue scratch

  // Q fragments: 2 m-tiles x 2 kt
  v8s aq[2][2];
#pragma unroll
  for (int mi = 0; mi < 2; ++mi) {
    const unsigned short* qp =
        Qb + (size_t)(b * 2048 + q0 + wq * 32 + mi * 16 + l16) * 768 + h * 64 +
        quad * 8;
    aq[mi][0] = *(const v8s*)qp;
    aq[mi][1] = *(const v8s*)(qp + 32);
  }

  v4f o[2][4], ol[2];
#pragma unroll
  for (int mi = 0; mi < 2; ++mi) {
#pragma unroll
    for (int nt = 0; nt < 4; ++nt) { v4f z = {0.f, 0.f, 0.f, 0.f}; o[mi][nt] = z; }
    v4f z = {0.f, 0.f, 0.f, 0.f}; ol[mi] = z;
  }

  // ones-column B fragment (col 0 only)
  v8s bones;
  {
    const short v1 = (l16 == 0) ? (short)0x3F80 : (short)0;
#pragma unroll
    for (int j = 0; j < 8; ++j) bones[j] = v1;
  }

  const int rsub = lane >> 3;
  const int csub = ((lane & 7) ^ rsub) * 8;  // swizzled source chunk
  const unsigned short* kg0 = Kb + (size_t)(b * 2048 + w * 16) * 768 + h * 64;
  const unsigned short* vg0 = Vt + (size_t)(b * 768 + h * 64 + w * 16) * 2048;
  const uint32_t* mg0 =
      mbits + (size_t)(b * 2048 + q0 + w * 32 + (lane >> 1)) * 64 + (lane & 1);

#define ATTN_STAGE(kk0, buf)                                                   \
  do {                                                                         \
    const unsigned short* kg = kg0 + (size_t)(kk0) * 768;                      \
    const unsigned short* vg = vg0 + (kk0);                                    \
    load16_to_lds(kg + (size_t)rsub * 768 + csub,                              \
                  &Kl[(buf) * 4096 + (w * 16) * 64]);                          \
    load16_to_lds(kg + (size_t)(8 + rsub) * 768 + csub,                        \
                  &Kl[(buf) * 4096 + (w * 16 + 8) * 64]);                      \
    load16_to_lds(vg + (size_t)rsub * 2048 + csub,                             \
                  &Vl[(buf) * 4096 + (w * 16) * 64]);                          \
    load16_to_lds(vg + (size_t)(8 + rsub) * 2048 + csub,                       \
                  &Vl[(buf) * 4096 + (w * 16 + 8) * 64]);                      \
    if (w < 2) load4_to_lds(mg0 + ((kk0) >> 5), &Ml[(buf) * 128 + w * 64]);    \
  } while (0)

  ATTN_STAGE(0, 0);
#pragma unroll 2
  for (int it = 0; it < 32; ++it) {
    const int bufc = it & 1;
    __syncthreads();

    // K fragments (only our 32-key half), then issue next tile's prefetch
    v8s bk[2][2];
#pragma unroll
    for (int ni = 0; ni < 2; ++ni)
#pragma unroll
      for (int kt = 0; kt < 2; ++kt)
        bk[ni][kt] = *(const v8s*)&Kl[bufc * 4096 +
                                      (wk * 32 + ni * 16 + l16) * 64 +
                                      (((kt * 4 + quad) ^ l7) << 3)];
    if (it < 31) ATTN_STAGE((it + 1) * 64, bufc ^ 1);

    // S = Q K^T : 32q x 32k per wave
    v4f sacc[2][2];
#pragma unroll
    for (int mi = 0; mi < 2; ++mi)
#pragma unroll
      for (int ni = 0; ni < 2; ++ni) {
        v4f z = {0.f, 0.f, 0.f, 0.f};
        sacc[mi][ni] = z;
      }
#pragma unroll
    for (int kt = 0; kt < 2; ++kt)
#pragma unroll
      for (int mi = 0; mi < 2; ++mi)
#pragma unroll
        for (int ni = 0; ni < 2; ++ni)
          sacc[mi][ni] = __builtin_amdgcn_mfma_f32_16x16x32_bf16(
              aq[mi][kt], bk[ni][kt], sacc[mi][ni], 0, 0, 0);

    // P = mask ? 0 : exp2(S); write our 32x32 quadrant of Pl (swizzled)
    const int hi = l16 >> 3;
#pragma unroll
    for (int mi = 0; mi < 2; ++mi) {
#pragma unroll
      for (int r = 0; r < 4; ++r) {
        const int row = wq * 32 + mi * 16 + quad * 4 + r;
        const uint32_t u = Ml[bufc * 128 + row * 2 + wk] >> l16;
        const float p0 = (u & 1u) ? 0.f : fexp2(sacc[mi][0][r]);
        const float p1 = ((u >> 16) & 1u) ? 0.f : fexp2(sacc[mi][1][r]);
        const int ps = (quad * 4 + r) & 7;
        const int base = row * 64 + l7;
        Pl[base + (((wk * 4 + 0 + hi) ^ ps) << 3)] = f2bf_rn(p0);
        Pl[base + (((wk * 4 + 2 + hi) ^ ps) << 3)] = f2bf_rn(p1);
      }
    }

    // O += P V over our 32 keys ; ol += P @ ones  (same wave wrote this P ->
    // program order, no barrier needed)
#pragma unroll
    for (int mi = 0; mi < 2; ++mi) {
      const v8s ap = *(const v8s*)&Pl[(wq * 32 + mi * 16 + l16) * 64 +
                                      (((wk * 4 + quad) ^ l7) << 3)];
#pragma unroll
      for (int nt = 0; nt < 4; ++nt) {
        const v8s bv = *(const v8s*)&Vl[bufc * 4096 + (nt * 16 + l16) * 64 +
                                        (((wk * 4 + quad) ^ l7) << 3)];
        o[mi][nt] =
            __builtin_amdgcn_mfma_f32_16x16x32_bf16(ap, bv, o[mi][nt], 0, 0, 0);
      }
      ol[mi] = __builtin_amdgcn_mfma_f32_16x16x32_bf16(ap, bones, ol[mi], 0, 0, 0);
    }
  }
#undef ATTN_STAGE

  // epilogue: combine wk=0 / wk=1 key-half partials via LDS, normalize, write.
  __syncthreads();  // Kl/Vl dead -> reuse as fp32 scratch
  const int sbase = (wq * 64 + lane) * 44;  // 176 B stride (16B-aligned)
  if (wk) {
#pragma unroll
    for (int mi = 0; mi < 2; ++mi)
#pragma unroll
      for (int nt = 0; nt < 4; ++nt)
        *(v4f*)&sc[sbase + (mi * 4 + nt) * 4] = o[mi][nt];
    *(v4f*)&sc[sbase + 32] = ol[0];
    *(v4f*)&sc[sbase + 36] = ol[1];
  }
  __syncthreads();
  if (!wk) {
#pragma unroll
    for (int mi = 0; mi < 2; ++mi)
#pragma unroll
      for (int nt = 0; nt < 4; ++nt)
        o[mi][nt] += *(const v4f*)&sc[sbase + (mi * 4 + nt) * 4];
    ol[0] += *(const v4f*)&sc[sbase + 32];
    ol[1] += *(const v4f*)&sc[sbase + 36];

    // faithful reshape scramble: 2h+b = 12*b2 + h2
    const int hb2 = 2 * h + b;
    const int b2 = (hb2 >= 12) ? 1 : 0;
    const int h2 = hb2 - 12 * b2;
#pragma unroll
    for (int mi = 0; mi < 2; ++mi) {
#pragma unroll
      for (int r = 0; r < 4; ++r) {
        const float lsum = __shfl(ol[mi][r], quad * 16, 64);
        const float inv_l = 1.f / lsum;
        const int q = q0 + wq * 32 + mi * 16 + quad * 4 + r;
#pragma unroll
        for (int nt = 0; nt < 4; ++nt) {
          const int d = nt * 16 + l16;
          const size_t f = (size_t)h2 * 262144 + (size_t)q * 128 + b2 * 64 + d;
          X[f] = f2bf_rn(o[mi][nt][r] * inv_l);
        }
      }
    }
  }
}

// ---------------------------------------------------------------------------
// Kernel 4: fused out = LN(X @ Wc^T + bc + query). Block = 16 rows x 768 cols,
// grid 256 (1 block/CU). Full Wc panel staged per k-step (dbuf, 96 KB), LN
// computed in-block (4-wave reduction). Eliminates the separate ln kernel.
// ---------------------------------------------------------------------------
__global__ __launch_bounds__(256, 1) void gemm2ln_kernel(
    const unsigned short* __restrict__ X, const unsigned short* __restrict__ Wcb,
    const float* __restrict__ bc, const float* __restrict__ query,
    const float* __restrict__ lng, const float* __restrict__ lnb,
    float* __restrict__ out) {
  const int m0 = blockIdx.x * 16;
  const int tid = threadIdx.x, lane = tid & 63, wid = tid >> 6;
  const int l16 = lane & 15, quad = lane >> 4;

  __shared__ __align__(16) unsigned short Bs[2][768 * 32];  // 96 KB
  __shared__ __align__(16) unsigned short As[2][16 * 32];   // 2 KB
  __shared__ float red_s[4][16], red_sq[4][16];

  v4f acc[12];
#pragma unroll
  for (int j = 0; j < 12; ++j) { v4f z = {0.f, 0.f, 0.f, 0.f}; acc[j] = z; }

  // A: 64 chunks staged by wave 0 ; B: 3072 chunks, 12/thread
  const unsigned short* a0 =
      X + (size_t)(m0 + (lane >> 2)) * 768 + (lane & 3) * 8;

#define G2_STAGE(k0, buf)                                                     \
  do {                                                                        \
    if (wid == 0) load16_to_lds(a0 + (k0), &As[buf][0]);                      \
    _Pragma("unroll") for (int i = 0; i < 12; ++i) {                          \
      const int c = wid * 768 + i * 64 + lane;                                \
      load16_to_lds(Wcb + (size_t)(c >> 2) * 768 + (k0) + (c & 3) * 8,        \
                    &Bs[buf][(wid * 768 + i * 64) * 8]);                      \
    }                                                                         \
  } while (0)

  G2_STAGE(0, 0);
#pragma unroll 2
  for (int ks = 0; ks < 24; ++ks) {
    const int bufc = ks & 1;
    __syncthreads();
    const v8s af = *(const v8s*)&As[bufc][l16 * 32 + quad * 8];
    v8s bf[12];
#pragma unroll
    for (int j = 0; j < 12; ++j)
      bf[j] = *(const v8s*)&Bs[bufc][(wid * 192 + j * 16 + l16) * 32 + quad * 8];
    if (ks < 23) G2_STAGE((ks + 1) * 32, bufc ^ 1);
#pragma unroll
    for (int j = 0; j < 12; ++j)
      acc[j] = __builtin_amdgcn_mfma_f32_16x16x32_bf16(af, bf[j], acc[j], 0, 0, 0);
  }
#undef G2_STAGE

  // epilogue: x = acc + bc + query ; LN over the full 768-row in-block
  float s[4] = {0.f, 0.f, 0.f, 0.f}, sq[4] = {0.f, 0.f, 0.f, 0.f};
#pragma unroll
  for (int j = 0; j < 12; ++j) {
    const int n = wid * 192 + j * 16 + l16;
    const float bv_ = bc[n];
#pragma unroll
    for (int r = 0; r < 4; ++r) {
      const int m = m0 + quad * 4 + r;
      const float x = acc[j][r] + bv_ + query[(size_t)m * 768 + n];
      acc[j][r] = x;
      s[r] += x;
      sq[r] += x * x;
    }
  }
#pragma unroll
  for (int off = 1; off < 16; off <<= 1) {
#pragma unroll
    for (int r = 0; r < 4; ++r) {
      s[r] += __shfl_xor(s[r], off, 64);
      sq[r] += __shfl_xor(sq[r], off, 64);
    }
  }
  if (l16 == 0) {
#pragma unroll
    for (int r = 0; r < 4; ++r) {
      red_s[wid][quad * 4 + r] = s[r];
      red_sq[wid][quad * 4 + r] = sq[r];
    }
  }
  __syncthreads();
#pragma unroll
  for (int r = 0; r < 4; ++r) {
    const int row = quad * 4 + r;
    const float ts = red_s[0][row] + red_s[1][row] + red_s[2][row] + red_s[3][row];
    const float tq = red_sq[0][row] + red_sq[1][row] + red_sq[2][row] + red_sq[3][row];
    const float mu = ts * (1.f / 768.f);
    const float var = tq * (1.f / 768.f) - mu * mu;
    const float rstd = rsqrtf(var + 1e-5f);
#pragma unroll
    for (int j = 0; j < 12; ++j) {
      const int n = wid * 192 + j * 16 + l16;
      out[(size_t)(m0 + row) * 768 + n] =
          lng[n] * (acc[j][r] - mu) * rstd + lnb[n];
    }
  }
}

// ---------------------------------------------------------------------------
extern "C" void kernel_launch(void* const* d_in, const int* in_sizes, int n_in,
                              void* d_out, int out_size, void* d_ws,
                              size_t ws_size, hipStream_t stream) {
  const float* key   = (const float*)d_in[0];
  const float* query = (const float*)d_in[1];
  const float* value = (const float*)d_in[2];
  const uint32_t* mask = (const uint32_t*)d_in[3];
  const float* Wk = (const float*)d_in[4];
  const float* bk = (const float*)d_in[5];
  const float* Wq = (const float*)d_in[6];
  const float* bq = (const float*)d_in[7];
  const float* Wv = (const float*)d_in[8];
  const float* bv = (const float*)d_in[9];
  const float* Wc = (const float*)d_in[10];
  const float* bc = (const float*)d_in[11];
  const float* lng = (const float*)d_in[12];
  const float* lnb = (const float*)d_in[13];

  char* ws = (char*)d_ws;
  uint32_t*       mbits = (uint32_t*)(ws);                   // 1 MB
  unsigned short* Wkb = (unsigned short*)(ws + 0x100000);    // 1.125 MB each
  unsigned short* Wqb = (unsigned short*)(ws + 0x220000);
  unsigned short* Wvb = (unsigned short*)(ws + 0x340000);
  unsigned short* Wcb = (unsigned short*)(ws + 0x460000);
  unsigned short* Qb  = (unsigned short*)(ws + 0x600000);    // 6 MB each
  unsigned short* Kb  = (unsigned short*)(ws + 0xC00000);
  unsigned short* Vt  = (unsigned short*)(ws + 0x1200000);
  unsigned short* X   = (unsigned short*)(ws + 0x1800000);   // also Vin (dead
                                                             // before X write)
  // bf16 input staging: Kin/Qin live in d_out (12.58 MB = exactly 2 buffers),
  // which is not written until gemm2ln.
  unsigned short* Kin = (unsigned short*)d_out;
  unsigned short* Qin = (unsigned short*)d_out + 3145728;
  unsigned short* Vin = X;
  float* out = (float*)d_out;

  conv_pack_kernel<<<dim3(3072, 8), dim3(256), 0, stream>>>(
      Wk, Wq, Wv, Wc, key, query, value, mask,
      Wkb, Wqb, Wvb, Wcb, Kin, Qin, Vin, mbits);
  gemm_qkv_kernel<<<dim3(32, 6, 3), dim3(256), 0, stream>>>(
      Qin, Kin, Vin, Wqb, Wkb, Wvb, bq, bk, bv, Qb, Kb, Vt);
  attn_kernel<<<dim3(32, 12, 2), dim3(256), 0, stream>>>(Qb, Kb, Vt, mbits, X);
  gemm2ln_kernel<<<dim3(256), dim3(256), 0, stream>>>(X, Wcb, bc, query, lng,
                                                      lnb, out);
}

// Round 5
// 241.178 us; speedup vs baseline: 1.0952x; 1.0952x over previous
//
#include <hip/hip_runtime.h>
#include <stdint.h>

// B=2, S=2048, D=768, H=12, hd=64
typedef float v4f __attribute__((ext_vector_type(4)));
typedef short v8s __attribute__((ext_vector_type(8)));

#define AS1 __attribute__((address_space(1)))
#define AS3 __attribute__((address_space(3)))

__device__ __forceinline__ void load16_to_lds(const void* g, void* l) {
  __builtin_amdgcn_global_load_lds((AS1 void*)g, (AS3 void*)l, 16, 0, 0);
}

__device__ __forceinline__ float fexp2(float x) {
#if __has_builtin(__builtin_amdgcn_exp2f)
  return __builtin_amdgcn_exp2f(x);
#else
  return exp2f(x);
#endif
}

// round-half-up fp32 -> bf16
__device__ __forceinline__ unsigned short f2bf_rn(float f) {
  union { float f; uint32_t u; } v; v.f = f;
  return (unsigned short)((v.u + 0x8000u) >> 16);
}
// pack two fp32 -> bf16x2 dword via v_perm (x in low half)
__device__ __forceinline__ uint32_t pack_bf2(float x, float y) {
  union { float f; uint32_t u; } a, b; a.f = x; b.f = y;
  return __builtin_amdgcn_perm(b.u + 0x8000u, a.u + 0x8000u, 0x07060302u);
}

#define QSCALE 0.052058786f  // log2(e)/sqrt(768), folded into Wq & bq

// ---------------------------------------------------------------------------
// Kernel 1: fused convert + mask pack, compact 1-D grid (12544 blocks):
//   [0,2304)      weights fp32->bf16 (576 blocks each; Wq scaled by QSCALE)
//   [2304,11520)  inputs fp32->bf16 (3072 blocks each)
//   [11520,12544) mask -> 1 bit/entry
// ---------------------------------------------------------------------------
__global__ __launch_bounds__(256) void conv_pack_kernel(
    const float* __restrict__ wk, const float* __restrict__ wq,
    const float* __restrict__ wv, const float* __restrict__ wc,
    const float* __restrict__ kin, const float* __restrict__ qin,
    const float* __restrict__ vin, const uint32_t* __restrict__ mask,
    unsigned short* __restrict__ dk, unsigned short* __restrict__ dq,
    unsigned short* __restrict__ dv, unsigned short* __restrict__ dc,
    unsigned short* __restrict__ dki, unsigned short* __restrict__ dqi,
    unsigned short* __restrict__ dvi, uint32_t* __restrict__ bits) {
  const int id = blockIdx.x;
  const int tid = threadIdx.x;
  if (id >= 11520) {  // mask pack
    const int xx = id - 11520;
    __shared__ int s_i32;
    if (tid == 0) s_i32 = 1;
    __syncthreads();
    if (mask[tid] > 1u) s_i32 = 0;  // byte-mode detector (P(fail)=8^-256)
    __syncthreads();
    if (s_i32) {
      const int lane = tid & 63;
      const int gw = (xx * 256 + tid) >> 6;  // 0..4095
#pragma unroll 4
      for (int it = 0; it < 32; ++it) {
        const size_t base = (size_t)gw * 2048 + it * 64;
        unsigned long long bal = __ballot(mask[base + lane] != 0u);
        if (lane == 0) *(unsigned long long*)&bits[base >> 5] = bal;
      }
    } else {
      const int wi = xx * 256 + tid;
      const uint32_t* p = mask + (size_t)wi * 8;
      uint32_t w = 0;
#pragma unroll
      for (int j8 = 0; j8 < 8; ++j8) {
        uint32_t u = p[j8];
#pragma unroll
        for (int k = 0; k < 4; ++k)
          w |= (((u >> (8 * k)) & 0xFFu) ? 1u : 0u) << (j8 * 4 + k);
      }
      bits[wi] = w;
    }
    return;
  }
  const float* s; unsigned short* d; float sc = 1.f; int x;
  if (id < 2304) {
    const int y = id / 576;
    x = id - y * 576;
    if (y == 0)      { s = wk; d = dk; }
    else if (y == 1) { s = wq; d = dq; sc = QSCALE; }
    else if (y == 2) { s = wv; d = dv; }
    else             { s = wc; d = dc; }
  } else {
    const int t = id - 2304;
    const int y = t / 3072;
    x = t - y * 3072;
    if (y == 0)      { s = kin; d = dki; }
    else if (y == 1) { s = qin; d = dqi; }
    else             { s = vin; d = dvi; }
  }
  const int i = x * 256 + tid;
  float4 f = ((const float4*)s)[i];
  uint2 o;
  o.x = pack_bf2(f.x * sc, f.y * sc);
  o.y = pack_bf2(f.z * sc, f.w * sc);
  ((uint2*)d)[i] = o;
}

// ---------------------------------------------------------------------------
// Kernel 2: QKV GEMM, all-bf16, global_load_lds staging, dbuf single-barrier.
// 128x128 tile, BK=32, 4 waves 4x4 MFMA.
// z=0: Qin*Wq(scaled) -> Qb ; z=1: Kin*Wk -> Kb ; z=2: Vin*Wv -> Vt (transposed)
// ---------------------------------------------------------------------------
__global__ __launch_bounds__(256, 3) void gemm_qkv_kernel(
    const unsigned short* __restrict__ qin, const unsigned short* __restrict__ kin,
    const unsigned short* __restrict__ vin,
    const unsigned short* __restrict__ wqb, const unsigned short* __restrict__ wkb,
    const unsigned short* __restrict__ wvb,
    const float* __restrict__ bq, const float* __restrict__ bk,
    const float* __restrict__ bv,
    unsigned short* __restrict__ Qb, unsigned short* __restrict__ Kb,
    unsigned short* __restrict__ Vt) {
  const int which = blockIdx.z;
  const unsigned short* A; const unsigned short* Wb; const float* bias;
  float bscale = 1.f;
  if (which == 0)      { A = qin; Wb = wqb; bias = bq; bscale = QSCALE; }
  else if (which == 1) { A = kin; Wb = wkb; bias = bk; }
  else                 { A = vin; Wb = wvb; bias = bv; }

  const int m0 = blockIdx.x * 128, n0 = blockIdx.y * 128;
  const int tid = threadIdx.x, lane = tid & 63, wid = tid >> 6;
  const int wm = wid >> 1, wn = wid & 1;
  const int l16 = lane & 15, quad = lane >> 4;

  __shared__ __align__(16) unsigned short As[2][128 * 32];
  __shared__ __align__(16) unsigned short Bs[2][128 * 32];

  v4f acc[4][4];
#pragma unroll
  for (int i = 0; i < 4; ++i)
#pragma unroll
    for (int j = 0; j < 4; ++j) { v4f z = {0.f, 0.f, 0.f, 0.f}; acc[i][j] = z; }

  const int c0 = wid * 128 + lane, c1 = wid * 128 + 64 + lane;
  const unsigned short* a0 = A + (size_t)(m0 + (c0 >> 2)) * 768 + (c0 & 3) * 8;
  const unsigned short* a1 = A + (size_t)(m0 + (c1 >> 2)) * 768 + (c1 & 3) * 8;
  const unsigned short* b0 = Wb + (size_t)(n0 + (c0 >> 2)) * 768 + (c0 & 3) * 8;
  const unsigned short* b1 = Wb + (size_t)(n0 + (c1 >> 2)) * 768 + (c1 & 3) * 8;

#define QKV_STAGE(k0, buf)                                         \
  do {                                                             \
    load16_to_lds(a0 + (k0), &As[buf][(wid * 128) * 8]);           \
    load16_to_lds(a1 + (k0), &As[buf][(wid * 128 + 64) * 8]);      \
    load16_to_lds(b0 + (k0), &Bs[buf][(wid * 128) * 8]);           \
    load16_to_lds(b1 + (k0), &Bs[buf][(wid * 128 + 64) * 8]);      \
  } while (0)

  QKV_STAGE(0, 0);
#pragma unroll 2
  for (int ks = 0; ks < 24; ++ks) {
    const int bufc = ks & 1;
    __syncthreads();
    v8s af[4], bf[4];
#pragma unroll
    for (int i = 0; i < 4; ++i)
      af[i] = *(const v8s*)&As[bufc][(wm * 64 + i * 16 + l16) * 32 + quad * 8];
#pragma unroll
    for (int j = 0; j < 4; ++j)
      bf[j] = *(const v8s*)&Bs[bufc][(wn * 64 + j * 16 + l16) * 32 + quad * 8];
    if (ks < 23) QKV_STAGE((ks + 1) * 32, bufc ^ 1);
#pragma unroll
    for (int i = 0; i < 4; ++i)
#pragma unroll
      for (int j = 0; j < 4; ++j)
        acc[i][j] = __builtin_amdgcn_mfma_f32_16x16x32_bf16(af[i], bf[j],
                                                            acc[i][j], 0, 0, 0);
  }
#undef QKV_STAGE

#pragma unroll
  for (int i = 0; i < 4; ++i) {
#pragma unroll
    for (int j = 0; j < 4; ++j) {
      const int mbase = m0 + wm * 64 + i * 16 + quad * 4;
      const int n = n0 + wn * 64 + j * 16 + l16;
      const float bv_ = bias[n] * bscale;
      if (which == 2) {
        const int bb = mbase >> 11, ss = mbase & 2047;
        uint2 pk;
        pk.x = pack_bf2(acc[i][j][0] + bv_, acc[i][j][1] + bv_);
        pk.y = pack_bf2(acc[i][j][2] + bv_, acc[i][j][3] + bv_);
        *(uint2*)&Vt[((size_t)bb * 768 + n) * 2048 + ss] = pk;
      } else {
        unsigned short* dst = (which == 0) ? Qb : Kb;
#pragma unroll
        for (int r = 0; r < 4; ++r)
          dst[(size_t)(mbase + r) * 768 + n] = f2bf_rn(acc[i][j][r] + bv_);
      }
    }
  }
}

// ---------------------------------------------------------------------------
// Kernel 3: attention, S^T formulation. QK MFMA computes S^T (A=K-frag,
// B=Q-frag), so each lane holds P for query q=l16 with 4 consecutive keys per
// reg quad: P writes are 4x ds_write_b64, mask is one register uint2/lane
// (prefetched global load, no LDS). PV reads P back as A-frags (b128).
// Denominator via ones-MFMA. XOR-swizzled LDS (conflict-free). LDS = 40960 B
// exactly -> 4 blocks/CU. grid (32,12,2) x 256.
// ---------------------------------------------------------------------------
__global__ __launch_bounds__(256, 4) void attn_kernel(
    const unsigned short* __restrict__ Qb, const unsigned short* __restrict__ Kb,
    const unsigned short* __restrict__ Vt, const uint32_t* __restrict__ mbits,
    unsigned short* __restrict__ X) {
  const int q0 = blockIdx.x * 64;
  const int h = blockIdx.y, b = blockIdx.z;
  const int tid = threadIdx.x, w = tid >> 6, lane = tid & 63;
  const int l16 = lane & 15, quad = lane >> 4, l7 = l16 & 7;

  __shared__ __align__(16) unsigned short Kl[2][64 * 64];  // 16 KB [key][dim]
  __shared__ __align__(16) unsigned short Vl[2][64 * 64];  // 16 KB [dim][key]
  __shared__ __align__(16) unsigned short Pl[4][16 * 64];  //  8 KB [q][key]

  // Q fragments (B-operand for S^T): lane l16 = q, dims quad*8..+7 (+32)
  v8s aq[2];
  {
    const unsigned short* qp =
        Qb + (size_t)(b * 2048 + q0 + w * 16 + l16) * 768 + h * 64 + quad * 8;
    aq[0] = *(const v8s*)qp;
    aq[1] = *(const v8s*)(qp + 32);
  }

  v4f o[4], ol;
#pragma unroll
  for (int nt = 0; nt < 4; ++nt) { v4f z = {0.f, 0.f, 0.f, 0.f}; o[nt] = z; }
  { v4f z = {0.f, 0.f, 0.f, 0.f}; ol = z; }

  // ones-column B fragment (col 0 only)
  v8s bones;
  {
    const short v1 = (l16 == 0) ? (short)0x3F80 : (short)0;
#pragma unroll
    for (int j = 0; j < 8; ++j) bones[j] = v1;
  }

  const int rsub = lane >> 3;
  const int csub = ((lane & 7) ^ rsub) * 8;  // swizzled source chunk
  const unsigned short* kg0 = Kb + (size_t)(b * 2048 + w * 16) * 768 + h * 64;
  const unsigned short* vg0 = Vt + (size_t)(b * 768 + h * 64 + w * 16) * 2048;
  // per-lane mask row: query q0 + w*16 + l16, 2 dwords per 64-key tile
  const uint2* mp =
      (const uint2*)(mbits + (size_t)(b * 2048 + q0 + w * 16 + l16) * 64);

#define ATTN_STAGE(kk0, buf)                                                   \
  do {                                                                         \
    const unsigned short* kg = kg0 + (size_t)(kk0) * 768;                      \
    const unsigned short* vg = vg0 + (kk0);                                    \
    load16_to_lds(kg + (size_t)rsub * 768 + csub, &Kl[buf][(w * 16) * 64]);    \
    load16_to_lds(kg + (size_t)(8 + rsub) * 768 + csub,                        \
                  &Kl[buf][(w * 16 + 8) * 64]);                                \
    load16_to_lds(vg + (size_t)rsub * 2048 + csub, &Vl[buf][(w * 16) * 64]);   \
    load16_to_lds(vg + (size_t)(8 + rsub) * 2048 + csub,                       \
                  &Vl[buf][(w * 16 + 8) * 64]);                                \
  } while (0)

  ATTN_STAGE(0, 0);
  uint2 mreg = mp[0];
#pragma unroll 2
  for (int it = 0; it < 32; ++it) {
    const int bufc = it & 1;
    __syncthreads();

    // K fragments (A-operand): lane l16 = key (tile nt), dims kt*32+quad*8..+7
    v8s bk[2][4];
#pragma unroll
    for (int kt = 0; kt < 2; ++kt)
#pragma unroll
      for (int nt = 0; nt < 4; ++nt)
        bk[kt][nt] = *(const v8s*)&Kl[bufc][(nt * 16 + l16) * 64 +
                                           (((kt * 4 + quad) ^ l7) << 3)];
    uint2 mnext;
    if (it < 31) {
      ATTN_STAGE((it + 1) * 64, bufc ^ 1);
      mnext = mp[it + 1];
    }

    // S^T = K Q^T : sacc[nt] rows = keys nt*16+quad*4+r, col = q = l16
    v4f sacc[4];
#pragma unroll
    for (int nt = 0; nt < 4; ++nt) { v4f z = {0.f, 0.f, 0.f, 0.f}; sacc[nt] = z; }
#pragma unroll
    for (int kt = 0; kt < 2; ++kt)
#pragma unroll
      for (int nt = 0; nt < 4; ++nt)
        sacc[nt] = __builtin_amdgcn_mfma_f32_16x16x32_bf16(bk[kt][nt], aq[kt],
                                                           sacc[nt], 0, 0, 0);

    // P = mask ? 0 : exp2(S); 4 consecutive keys per (nt) -> one b64 write
    const uint32_t u[4] = {mreg.x >> (quad * 4), mreg.x >> (quad * 4 + 16),
                           mreg.y >> (quad * 4), mreg.y >> (quad * 4 + 16)};
#pragma unroll
    for (int nt = 0; nt < 4; ++nt) {
      const float p0 = (u[nt] & 1u) ? 0.f : fexp2(sacc[nt][0]);
      const float p1 = ((u[nt] >> 1) & 1u) ? 0.f : fexp2(sacc[nt][1]);
      const float p2 = ((u[nt] >> 2) & 1u) ? 0.f : fexp2(sacc[nt][2]);
      const float p3 = ((u[nt] >> 3) & 1u) ? 0.f : fexp2(sacc[nt][3]);
      uint2 pk;
      pk.x = pack_bf2(p0, p1);
      pk.y = pack_bf2(p2, p3);
      // keys nt*16 + quad*4 + 0..3 of row q=l16, chunk-xor swizzled
      const int elem =
          l16 * 64 + (((nt * 2 + (quad >> 1)) ^ l7) << 3) + (quad & 1) * 4;
      *(uint2*)&Pl[w][elem] = pk;
    }

    // O += P V ; ol += P @ ones (same-wave LDS ordering, no barrier)
#pragma unroll
    for (int kt = 0; kt < 2; ++kt) {
      const v8s ap = *(const v8s*)&Pl[w][l16 * 64 + (((kt * 4 + quad) ^ l7) << 3)];
#pragma unroll
      for (int nt = 0; nt < 4; ++nt) {
        const v8s bv = *(const v8s*)&Vl[bufc][(nt * 16 + l16) * 64 +
                                             (((kt * 4 + quad) ^ l7) << 3)];
        o[nt] = __builtin_amdgcn_mfma_f32_16x16x32_bf16(ap, bv, o[nt], 0, 0, 0);
      }
      ol = __builtin_amdgcn_mfma_f32_16x16x32_bf16(ap, bones, ol, 0, 0, 0);
    }
    mreg = mnext;
  }
#undef ATTN_STAGE

  // epilogue: faithful reshape scramble. 2h+b = 12*b2 + h2
  const int hb2 = 2 * h + b;
  const int b2 = (hb2 >= 12) ? 1 : 0;
  const int h2 = hb2 - 12 * b2;
#pragma unroll
  for (int r = 0; r < 4; ++r) {
    const float lsum = __shfl(ol[r], quad * 16, 64);  // col 0 holds the row sum
    const float inv_l = 1.f / lsum;
    const int q = q0 + w * 16 + quad * 4 + r;
#pragma unroll
    for (int nt = 0; nt < 4; ++nt) {
      const int d = nt * 16 + l16;
      const size_t f = (size_t)h2 * 262144 + (size_t)q * 128 + b2 * 64 + d;
      X[f] = f2bf_rn(o[nt][r] * inv_l);
    }
  }
}

// ---------------------------------------------------------------------------
// Kernel 4: out = X(bf16) @ Wc^T(bf16) + bc + query. 64x128 tile, dbuf
// prefetch loop. grid (64, 6).
// ---------------------------------------------------------------------------
__global__ __launch_bounds__(256, 3) void gemm2_kernel(
    const unsigned short* __restrict__ X, const unsigned short* __restrict__ Wcb,
    const float* __restrict__ bc, const float* __restrict__ query,
    float* __restrict__ out) {
  const int m0 = blockIdx.x * 64, n0 = blockIdx.y * 128;
  const int tid = threadIdx.x, lane = tid & 63, wid = tid >> 6;
  const int wm = wid >> 1, wn = wid & 1;
  const int l16 = lane & 15, quad = lane >> 4;

  __shared__ __align__(16) unsigned short As[2][64 * 32];
  __shared__ __align__(16) unsigned short Bs[2][128 * 32];

  v4f acc[2][4];
#pragma unroll
  for (int i = 0; i < 2; ++i)
#pragma unroll
    for (int j = 0; j < 4; ++j) { v4f z = {0.f, 0.f, 0.f, 0.f}; acc[i][j] = z; }

  const int ca = tid;  // A chunk
  const unsigned short* a0 = X + (size_t)(m0 + (ca >> 2)) * 768 + (ca & 3) * 8;
  const int c0 = wid * 128 + lane, c1 = wid * 128 + 64 + lane;
  const unsigned short* b0 = Wcb + (size_t)(n0 + (c0 >> 2)) * 768 + (c0 & 3) * 8;
  const unsigned short* b1 = Wcb + (size_t)(n0 + (c1 >> 2)) * 768 + (c1 & 3) * 8;

#define G2_STAGE(k0, buf)                                        \
  do {                                                           \
    load16_to_lds(a0 + (k0), &As[buf][(wid * 64) * 8]);          \
    load16_to_lds(b0 + (k0), &Bs[buf][(wid * 128) * 8]);         \
    load16_to_lds(b1 + (k0), &Bs[buf][(wid * 128 + 64) * 8]);    \
  } while (0)

  G2_STAGE(0, 0);
#pragma unroll 2
  for (int ks = 0; ks < 24; ++ks) {
    const int bufc = ks & 1;
    __syncthreads();
    v8s af[2], bf[4];
#pragma unroll
    for (int i = 0; i < 2; ++i)
      af[i] = *(const v8s*)&As[bufc][(wm * 32 + i * 16 + l16) * 32 + quad * 8];
#pragma unroll
    for (int j = 0; j < 4; ++j)
      bf[j] = *(const v8s*)&Bs[bufc][(wn * 64 + j * 16 + l16) * 32 + quad * 8];
    if (ks < 23) G2_STAGE((ks + 1) * 32, bufc ^ 1);
#pragma unroll
    for (int i = 0; i < 2; ++i)
#pragma unroll
      for (int j = 0; j < 4; ++j)
        acc[i][j] = __builtin_amdgcn_mfma_f32_16x16x32_bf16(af[i], bf[j],
                                                            acc[i][j], 0, 0, 0);
  }
#undef G2_STAGE

#pragma unroll
  for (int i = 0; i < 2; ++i) {
#pragma unroll
    for (int j = 0; j < 4; ++j) {
      const int mbase = m0 + wm * 32 + i * 16 + quad * 4;
      const int n = n0 + wn * 64 + j * 16 + l16;
      const float bv_ = bc[n];
#pragma unroll
      for (int r = 0; r < 4; ++r) {
        const int m = mbase + r;
        out[(size_t)m * 768 + n] =
            acc[i][j][r] + bv_ + query[(size_t)m * 768 + n];
      }
    }
  }
}

// ---------------------------------------------------------------------------
// Kernel 5: LayerNorm in place. One block per row.
// ---------------------------------------------------------------------------
__global__ __launch_bounds__(256) void ln_kernel(float* __restrict__ out,
                                                 const float* __restrict__ g,
                                                 const float* __restrict__ bta) {
  const int row = blockIdx.x;
  const int tid = threadIdx.x;
  float x[3];
  float s = 0.f, sq = 0.f;
#pragma unroll
  for (int k = 0; k < 3; ++k) {
    x[k] = out[(size_t)row * 768 + tid + k * 256];
    s += x[k];
    sq += x[k] * x[k];
  }
#pragma unroll
  for (int off = 1; off < 64; off <<= 1) {
    s += __shfl_xor(s, off, 64);
    sq += __shfl_xor(sq, off, 64);
  }
  __shared__ float ss[4], ssq[4];
  const int w = tid >> 6, lane = tid & 63;
  if (lane == 0) { ss[w] = s; ssq[w] = sq; }
  __syncthreads();
  s = ss[0] + ss[1] + ss[2] + ss[3];
  sq = ssq[0] + ssq[1] + ssq[2] + ssq[3];
  const float mu = s * (1.f / 768.f);
  const float var = sq * (1.f / 768.f) - mu * mu;
  const float rstd = rsqrtf(var + 1e-5f);
#pragma unroll
  for (int k = 0; k < 3; ++k) {
    const int cc = tid + k * 256;
    out[(size_t)row * 768 + cc] = g[cc] * (x[k] - mu) * rstd + bta[cc];
  }
}

// ---------------------------------------------------------------------------
extern "C" void kernel_launch(void* const* d_in, const int* in_sizes, int n_in,
                              void* d_out, int out_size, void* d_ws,
                              size_t ws_size, hipStream_t stream) {
  const float* key   = (const float*)d_in[0];
  const float* query = (const float*)d_in[1];
  const float* value = (const float*)d_in[2];
  const uint32_t* mask = (const uint32_t*)d_in[3];
  const float* Wk = (const float*)d_in[4];
  const float* bk = (const float*)d_in[5];
  const float* Wq = (const float*)d_in[6];
  const float* bq = (const float*)d_in[7];
  const float* Wv = (const float*)d_in[8];
  const float* bv = (const float*)d_in[9];
  const float* Wc = (const float*)d_in[10];
  const float* bc = (const float*)d_in[11];
  const float* lng = (const float*)d_in[12];
  const float* lnb = (const float*)d_in[13];

  char* ws = (char*)d_ws;
  uint32_t*       mbits = (uint32_t*)(ws);                   // 1 MB
  unsigned short* Wkb = (unsigned short*)(ws + 0x100000);    // 1.125 MB each
  unsigned short* Wqb = (unsigned short*)(ws + 0x220000);
  unsigned short* Wvb = (unsigned short*)(ws + 0x340000);
  unsigned short* Wcb = (unsigned short*)(ws + 0x460000);
  unsigned short* Qb  = (unsigned short*)(ws + 0x600000);    // 6 MB each
  unsigned short* Kb  = (unsigned short*)(ws + 0xC00000);
  unsigned short* Vt  = (unsigned short*)(ws + 0x1200000);
  unsigned short* X   = (unsigned short*)(ws + 0x1800000);   // also Vin (dead
                                                             // before X write)
  // bf16 input staging: Kin/Qin live in d_out (12.58 MB = exactly 2 buffers),
  // which is not written until gemm2.
  unsigned short* Kin = (unsigned short*)d_out;
  unsigned short* Qin = (unsigned short*)d_out + 3145728;
  unsigned short* Vin = X;
  float* out = (float*)d_out;

  conv_pack_kernel<<<dim3(12544), dim3(256), 0, stream>>>(
      Wk, Wq, Wv, Wc, key, query, value, mask,
      Wkb, Wqb, Wvb, Wcb, Kin, Qin, Vin, mbits);
  gemm_qkv_kernel<<<dim3(32, 6, 3), dim3(256), 0, stream>>>(
      Qin, Kin, Vin, Wqb, Wkb, Wvb, bq, bk, bv, Qb, Kb, Vt);
  attn_kernel<<<dim3(32, 12, 2), dim3(256), 0, stream>>>(Qb, Kb, Vt, mbits, X);
  gemm2_kernel<<<dim3(64, 6), dim3(256), 0, stream>>>(X, Wcb, bc, query, out);
  ln_kernel<<<dim3(4096), dim3(256), 0, stream>>>(out, lng, lnb);
}